// Round 2
// baseline (861.436 us; speedup 1.0000x reference)
//
#include <hip/hip_runtime.h>
#include <stdint.h>

typedef __bf16 bf16_t;
typedef __bf16 bf16x8 __attribute__((ext_vector_type(8)));
typedef __bf16 bf16x4 __attribute__((ext_vector_type(4)));
typedef float f32x4 __attribute__((ext_vector_type(4)));

#define GLL16(g, l)                                                                   \
  __builtin_amdgcn_global_load_lds((const __attribute__((address_space(1))) uint32_t*)(g), \
                                   (__attribute__((address_space(3))) uint32_t*)(l),  \
                                   16, 0, 0)

// ---------------------------------------------------------------------------
// 128x128 GEMM tile mainloop. C(128x128) += A(128xK) * B(128xK)^T
// A,B row-major bf16, leading dims lda/ldb. LDS chunk c = kq*128+row, 16B each.
// ---------------------------------------------------------------------------
__device__ __forceinline__ void gemm_tile(const bf16_t* __restrict__ A, long lda,
                                          const bf16_t* __restrict__ B, long ldb,
                                          int kTiles, bf16_t* lA, bf16_t* lB,
                                          f32x4 acc[4][4])
{
  const int tid  = threadIdx.x;
  const int wave = tid >> 6;
  const int lane = tid & 63;

  const bf16_t* pA[4];
  const bf16_t* pB[4];
  bf16_t* lAb[4];
  bf16_t* lBb[4];
#pragma unroll
  for (int i = 0; i < 4; ++i) {
    int c  = i * 256 + wave * 64 + lane;   // chunk id 0..1023
    int m  = c & 127;                      // row within tile
    int kq = c >> 7;                       // k-octet within BK=64
    pA[i]  = A + (long)m * lda + kq * 8;
    pB[i]  = B + (long)m * ldb + kq * 8;
    int cb = i * 256 + wave * 64;          // wave-uniform chunk base
    lAb[i] = lA + (long)cb * 8;
    lBb[i] = lB + (long)cb * 8;
  }
  const int lm = lane & 15;
  const int q  = lane >> 4;
  const int wi = (wave >> 1) * 64;
  const int wj = (wave & 1) * 64;

  for (int kt = 0; kt < kTiles; ++kt) {
    long ko = (long)kt * 64;
#pragma unroll
    for (int i = 0; i < 4; ++i) GLL16(pA[i] + ko, lAb[i]);
#pragma unroll
    for (int i = 0; i < 4; ++i) GLL16(pB[i] + ko, lBb[i]);
    __syncthreads();
#pragma unroll
    for (int s = 0; s < 2; ++s) {
      bf16x8 af[4], bfr[4];
#pragma unroll
      for (int i = 0; i < 4; ++i)
        af[i] = *(const bf16x8*)(lA + (((s * 4 + q) * 128) + wi + i * 16 + lm) * 8);
#pragma unroll
      for (int j = 0; j < 4; ++j)
        bfr[j] = *(const bf16x8*)(lB + (((s * 4 + q) * 128) + wj + j * 16 + lm) * 8);
#pragma unroll
      for (int i = 0; i < 4; ++i)
#pragma unroll
        for (int j = 0; j < 4; ++j)
          acc[i][j] = __builtin_amdgcn_mfma_f32_16x16x32_bf16(af[i], bfr[j], acc[i][j], 0, 0, 0);
    }
    __syncthreads();
  }
}

#define EPI_COORDS                              \
  const int tid  = threadIdx.x;                 \
  const int wave = tid >> 6;                    \
  const int lane = tid & 63;                    \
  const int lm   = lane & 15;                   \
  const int q    = lane >> 4;                   \
  const int wi   = (wave >> 1) * 64;            \
  const int wj   = (wave & 1) * 64;

#define ZERO_ACC(acc)                                            \
  _Pragma("unroll") for (int i = 0; i < 4; ++i)                  \
  _Pragma("unroll") for (int j = 0; j < 4; ++j)                  \
    acc[i][j] = (f32x4){0.f, 0.f, 0.f, 0.f};

// ---- convert fp32 -> bf16 hi/lo split, elementwise (vector x4)
__global__ __launch_bounds__(256) void k_cvt_split(const float* __restrict__ src,
                                                   bf16_t* __restrict__ hi,
                                                   bf16_t* __restrict__ lo)
{
  long i = ((long)blockIdx.x * 256 + threadIdx.x) * 4;
  float4 v = *(const float4*)(src + i);
  bf16_t h0 = (bf16_t)v.x, h1 = (bf16_t)v.y, h2 = (bf16_t)v.z, h3 = (bf16_t)v.w;
  bf16x4 hv = {h0, h1, h2, h3};
  bf16x4 lv = {(bf16_t)(v.x - (float)h0), (bf16_t)(v.y - (float)h1),
               (bf16_t)(v.z - (float)h2), (bf16_t)(v.w - (float)h3)};
  *(bf16x4*)(hi + i) = hv;
  *(bf16x4*)(lo + i) = lv;
}

// ---- fp32 transpose (R x C) -> bf16 (C x R) hi (+ optional lo), batched z
__global__ __launch_bounds__(256) void k_transpose_cvt(const float* __restrict__ src,
                                                       bf16_t* __restrict__ hi,
                                                       bf16_t* __restrict__ lo,
                                                       int R, int C)
{
  __shared__ float t[32][33];
  long bofs = (long)blockIdx.z * R * C;
  int x = blockIdx.x * 32 + threadIdx.x;
  int y = blockIdx.y * 32 + threadIdx.y;
#pragma unroll
  for (int j = 0; j < 32; j += 8)
    t[threadIdx.y + j][threadIdx.x] = src[bofs + (long)(y + j) * C + x];
  __syncthreads();
  int x2 = blockIdx.y * 32 + threadIdx.x;
  int y2 = blockIdx.x * 32 + threadIdx.y;
#pragma unroll
  for (int j = 0; j < 32; j += 8) {
    float v  = t[threadIdx.x][threadIdx.y + j];
    long idx = bofs + (long)(y2 + j) * R + x2;
    bf16_t h = (bf16_t)v;
    hi[idx] = h;
    if (lo) lo[idx] = (bf16_t)(v - (float)h);
  }
}

// ---- GEMM1: T = node @ W, 3-pass hi/lo -> fp32-accurate, stored as hi/lo bf16
__global__ __launch_bounds__(256, 2) void k_gemm_tw(const bf16_t* __restrict__ nh,
                                                    const bf16_t* __restrict__ nl,
                                                    const bf16_t* __restrict__ WTh,
                                                    const bf16_t* __restrict__ WTl,
                                                    bf16_t* __restrict__ Thi,
                                                    bf16_t* __restrict__ Tlo)
{
  __shared__ __align__(16) bf16_t lA[128 * 64];
  __shared__ __align__(16) bf16_t lB[128 * 64];
  f32x4 acc[4][4];
  ZERO_ACC(acc);
  long aofs = (long)blockIdx.x * 128 * 768;
  long bofs = (long)blockIdx.y * 128 * 768;
  gemm_tile(nh + aofs, 768, WTh + bofs, 768, 12, lA, lB, acc);
  gemm_tile(nl + aofs, 768, WTh + bofs, 768, 12, lA, lB, acc);
  gemm_tile(nh + aofs, 768, WTl + bofs, 768, 12, lA, lB, acc);
  EPI_COORDS;
  long row0 = (long)blockIdx.x * 128;
  long col0 = (long)blockIdx.y * 128;
#pragma unroll
  for (int i = 0; i < 4; ++i)
#pragma unroll
    for (int j = 0; j < 4; ++j)
#pragma unroll
      for (int r = 0; r < 4; ++r) {
        long row = row0 + wi + i * 16 + q * 4 + r;
        long col = col0 + wj + j * 16 + lm;
        float v  = acc[i][j][r];
        bf16_t h = (bf16_t)v;
        Thi[row * 768 + col] = h;
        Tlo[row * 768 + col] = (bf16_t)(v - (float)h);
      }
}

// ---- GEMM2: S = T @ node^T (3-pass hi/lo), masked by adj, fp32 out
__global__ __launch_bounds__(256, 2) void k_gemm_scores(const bf16_t* __restrict__ Thi,
                                                        const bf16_t* __restrict__ Tlo,
                                                        const bf16_t* __restrict__ nh,
                                                        const bf16_t* __restrict__ nl,
                                                        const int* __restrict__ adj,
                                                        float* __restrict__ S)
{
  __shared__ __align__(16) bf16_t lA[128 * 64];
  __shared__ __align__(16) bf16_t lB[128 * 64];
  f32x4 acc[4][4];
  ZERO_ACC(acc);
  const int b = blockIdx.z;
  long arow = ((long)b * 1024 + (long)blockIdx.x * 128) * 768;
  long brow = ((long)b * 1024 + (long)blockIdx.y * 128) * 768;
  gemm_tile(Thi + arow, 768, nh + brow, 768, 12, lA, lB, acc);
  gemm_tile(Tlo + arow, 768, nh + brow, 768, 12, lA, lB, acc);
  gemm_tile(Thi + arow, 768, nl + brow, 768, 12, lA, lB, acc);
  EPI_COORDS;
  const int* adjb = adj + (long)b * 1024 * 1024;
  float* Sb = S + (long)b * 1024 * 1024;
  long row0 = (long)blockIdx.x * 128;
  long col0 = (long)blockIdx.y * 128;
#pragma unroll
  for (int i = 0; i < 4; ++i)
#pragma unroll
    for (int j = 0; j < 4; ++j)
#pragma unroll
      for (int r = 0; r < 4; ++r) {
        long row = row0 + wi + i * 16 + q * 4 + r;
        long col = col0 + wj + j * 16 + lm;
        float v  = acc[i][j][r];
        v = (adjb[row * 1024 + col] == 1) ? v : -1e7f;
        Sb[row * 1024 + col] = v;
      }
}

// ---- row softmax: fp32 S[8192][1024] -> bf16 att
__global__ __launch_bounds__(256) void k_softmax(const float* __restrict__ S,
                                                 bf16_t* __restrict__ att)
{
  long row = blockIdx.x;
  const float4* p = (const float4*)(S + row * 1024);
  float4 v = p[threadIdx.x];
  float m = fmaxf(fmaxf(v.x, v.y), fmaxf(v.z, v.w));
#pragma unroll
  for (int off = 32; off; off >>= 1) m = fmaxf(m, __shfl_xor(m, off));
  __shared__ float redm[4];
  __shared__ float reds[4];
  int wave = threadIdx.x >> 6, lane = threadIdx.x & 63;
  if (lane == 0) redm[wave] = m;
  __syncthreads();
  m = fmaxf(fmaxf(redm[0], redm[1]), fmaxf(redm[2], redm[3]));
  float e0 = __expf(v.x - m), e1 = __expf(v.y - m), e2 = __expf(v.z - m), e3 = __expf(v.w - m);
  float s = e0 + e1 + e2 + e3;
#pragma unroll
  for (int off = 32; off; off >>= 1) s += __shfl_xor(s, off);
  if (lane == 0) reds[wave] = s;
  __syncthreads();
  s = reds[0] + reds[1] + reds[2] + reds[3];
  float inv = 1.0f / s;
  bf16x4 o = {(bf16_t)(e0 * inv), (bf16_t)(e1 * inv), (bf16_t)(e2 * inv), (bf16_t)(e3 * inv)};
  *(bf16x4*)(att + row * 1024 + threadIdx.x * 4) = o;
}

// ---- GEMM4: O = att @ node  -> wcat[:, branch*768 : +768]
__global__ __launch_bounds__(256, 2) void k_gemm_pv(const bf16_t* __restrict__ att,
                                                    const bf16_t* __restrict__ nodeT,
                                                    bf16_t* __restrict__ wcat, int branch)
{
  __shared__ __align__(16) bf16_t lA[128 * 64];
  __shared__ __align__(16) bf16_t lB[128 * 64];
  f32x4 acc[4][4];
  ZERO_ACC(acc);
  const int b = blockIdx.z;
  const bf16_t* A = att + ((long)b * 1024 + (long)blockIdx.x * 128) * 1024;
  const bf16_t* B = nodeT + ((long)b * 768 + (long)blockIdx.y * 128) * 1024;
  gemm_tile(A, 1024, B, 1024, 16, lA, lB, acc);
  EPI_COORDS;
  bf16_t* C = wcat + (long)b * 1024 * 2304 + branch * 768;
  long row0 = (long)blockIdx.x * 128;
  long col0 = (long)blockIdx.y * 128;
#pragma unroll
  for (int i = 0; i < 4; ++i)
#pragma unroll
    for (int j = 0; j < 4; ++j)
#pragma unroll
      for (int r = 0; r < 4; ++r) {
        long row = row0 + wi + i * 16 + q * 4 + r;
        long col = col0 + wj + j * 16 + lm;
        C[row * 2304 + col] = (bf16_t)acc[i][j][r];
      }
}

// ---- GEMM5: out = wcat @ params (fp32 output)
__global__ __launch_bounds__(256, 2) void k_gemm_final(const bf16_t* __restrict__ wcat,
                                                       const bf16_t* __restrict__ paramsT,
                                                       float* __restrict__ out)
{
  __shared__ __align__(16) bf16_t lA[128 * 64];
  __shared__ __align__(16) bf16_t lB[128 * 64];
  f32x4 acc[4][4];
  ZERO_ACC(acc);
  const bf16_t* A = wcat + (long)blockIdx.x * 128 * 2304;
  const bf16_t* B = paramsT + (long)blockIdx.y * 128 * 2304;
  gemm_tile(A, 2304, B, 2304, 36, lA, lB, acc);
  EPI_COORDS;
  long row0 = (long)blockIdx.x * 128;
  long col0 = (long)blockIdx.y * 128;
#pragma unroll
  for (int i = 0; i < 4; ++i)
#pragma unroll
    for (int j = 0; j < 4; ++j)
#pragma unroll
      for (int r = 0; r < 4; ++r) {
        long row = row0 + wi + i * 16 + q * 4 + r;
        long col = col0 + wj + j * 16 + lm;
        out[row * 768 + col] = acc[i][j][r];
      }
}

extern "C" void kernel_launch(void* const* d_in, const int* in_sizes, int n_in,
                              void* d_out, int out_size, void* d_ws, size_t ws_size,
                              hipStream_t stream)
{
  const float* node    = (const float*)d_in[0];
  const int*   adjp[3] = {(const int*)d_in[1], (const int*)d_in[2], (const int*)d_in[3]};
  const float* Wp[3]   = {(const float*)d_in[4], (const float*)d_in[5], (const float*)d_in[6]};
  const float* params  = (const float*)d_in[7];
  float* out = (float*)d_out;

  const size_t SZ_WT  = 768ull * 768 * 2;        // one bf16 [768][768]
  const size_t SZ_PT  = 768ull * 2304 * 2;       // bf16 [768][2304]
  const size_t SZ_N   = 8ull * 1024 * 768 * 2;   // bf16 [8192][768]
  const size_t SZ_NT  = 8ull * 768 * 1024 * 2;   // bf16 [8][768][1024]
  const size_t SZ_T   = 8ull * 1024 * 768 * 2;
  const size_t SZ_S   = 8ull * 1024 * 1024 * 4;
  const size_t SZ_ATT = 8ull * 1024 * 1024 * 2;
  const size_t SZ_WC  = 8ull * 1024 * 2304 * 2;
  const size_t TOTAL  = 6 * SZ_WT + SZ_PT + 2 * SZ_N + SZ_NT + 2 * SZ_T + SZ_S + SZ_ATT + SZ_WC;
  if (ws_size < TOTAL) return;  // diagnostic: output stays zero -> absmax == max|ref|

  char* base = (char*)d_ws;
  size_t off = 0;
  bf16_t* WTh[3];
  bf16_t* WTl[3];
  for (int i = 0; i < 3; ++i) { WTh[i] = (bf16_t*)(base + off); off += SZ_WT; }
  for (int i = 0; i < 3; ++i) { WTl[i] = (bf16_t*)(base + off); off += SZ_WT; }
  bf16_t* paramsT = (bf16_t*)(base + off); off += SZ_PT;
  bf16_t* node_hi = (bf16_t*)(base + off); off += SZ_N;
  bf16_t* node_lo = (bf16_t*)(base + off); off += SZ_N;
  bf16_t* nodeT   = (bf16_t*)(base + off); off += SZ_NT;
  bf16_t* Thi     = (bf16_t*)(base + off); off += SZ_T;
  bf16_t* Tlo     = (bf16_t*)(base + off); off += SZ_T;
  float*  S       = (float*)(base + off);  off += SZ_S;
  bf16_t* att     = (bf16_t*)(base + off); off += SZ_ATT;
  bf16_t* wcat    = (bf16_t*)(base + off); off += SZ_WC;

  dim3 tb(32, 8);
  // node fp32 -> bf16 hi/lo (row-major) and bf16 transpose
  k_cvt_split<<<6144, 256, 0, stream>>>(node, node_hi, node_lo);
  k_transpose_cvt<<<dim3(24, 32, 8), tb, 0, stream>>>(node, nodeT, nullptr, 1024, 768);
  for (int br = 0; br < 3; ++br)
    k_transpose_cvt<<<dim3(24, 24, 1), tb, 0, stream>>>(Wp[br], WTh[br], WTl[br], 768, 768);
  k_transpose_cvt<<<dim3(24, 72, 1), tb, 0, stream>>>(params, paramsT, nullptr, 2304, 768);

  for (int br = 0; br < 3; ++br) {
    k_gemm_tw<<<dim3(64, 6), 256, 0, stream>>>(node_hi, node_lo, WTh[br], WTl[br], Thi, Tlo);
    k_gemm_scores<<<dim3(8, 8, 8), 256, 0, stream>>>(Thi, Tlo, node_hi, node_lo, adjp[br], S);
    k_softmax<<<8192, 256, 0, stream>>>(S, att);
    k_gemm_pv<<<dim3(8, 6, 8), 256, 0, stream>>>(att, nodeT, wcat, br);
  }
  k_gemm_final<<<dim3(64, 6), 256, 0, stream>>>(wcat, paramsT, out);
}

// Round 3
// 855.391 us; speedup vs baseline: 1.0071x; 1.0071x over previous
//
#include <hip/hip_runtime.h>
#include <stdint.h>

typedef __bf16 bf16_t;
typedef __bf16 bf16x8 __attribute__((ext_vector_type(8)));
typedef __bf16 bf16x4 __attribute__((ext_vector_type(4)));
typedef float f32x4 __attribute__((ext_vector_type(4)));

#define GLL16(g, l)                                                                   \
  __builtin_amdgcn_global_load_lds((const __attribute__((address_space(1))) uint32_t*)(g), \
                                   (__attribute__((address_space(3))) uint32_t*)(l),  \
                                   16, 0, 0)

// ---------------------------------------------------------------------------
// 128x128 GEMM tile mainloop. C(128x128) += A(128xK) * B(128xK)^T
// A,B row-major bf16, leading dims lda/ldb. LDS chunk c = kq*128+row, 16B each.
// ---------------------------------------------------------------------------
__device__ __forceinline__ void gemm_tile(const bf16_t* __restrict__ A, long lda,
                                          const bf16_t* __restrict__ B, long ldb,
                                          int kTiles, bf16_t* lA, bf16_t* lB,
                                          f32x4 acc[4][4])
{
  const int tid  = threadIdx.x;
  const int wave = tid >> 6;
  const int lane = tid & 63;

  const bf16_t* pA[4];
  const bf16_t* pB[4];
  bf16_t* lAb[4];
  bf16_t* lBb[4];
#pragma unroll
  for (int i = 0; i < 4; ++i) {
    int c  = i * 256 + wave * 64 + lane;   // chunk id 0..1023
    int m  = c & 127;                      // row within tile
    int kq = c >> 7;                       // k-octet within BK=64
    pA[i]  = A + (long)m * lda + kq * 8;
    pB[i]  = B + (long)m * ldb + kq * 8;
    int cb = i * 256 + wave * 64;          // wave-uniform chunk base
    lAb[i] = lA + (long)cb * 8;
    lBb[i] = lB + (long)cb * 8;
  }
  const int lm = lane & 15;
  const int q  = lane >> 4;
  const int wi = (wave >> 1) * 64;
  const int wj = (wave & 1) * 64;

  for (int kt = 0; kt < kTiles; ++kt) {
    long ko = (long)kt * 64;
#pragma unroll
    for (int i = 0; i < 4; ++i) GLL16(pA[i] + ko, lAb[i]);
#pragma unroll
    for (int i = 0; i < 4; ++i) GLL16(pB[i] + ko, lBb[i]);
    __syncthreads();
#pragma unroll
    for (int s = 0; s < 2; ++s) {
      bf16x8 af[4], bfr[4];
#pragma unroll
      for (int i = 0; i < 4; ++i)
        af[i] = *(const bf16x8*)(lA + (((s * 4 + q) * 128) + wi + i * 16 + lm) * 8);
#pragma unroll
      for (int j = 0; j < 4; ++j)
        bfr[j] = *(const bf16x8*)(lB + (((s * 4 + q) * 128) + wj + j * 16 + lm) * 8);
#pragma unroll
      for (int i = 0; i < 4; ++i)
#pragma unroll
        for (int j = 0; j < 4; ++j)
          acc[i][j] = __builtin_amdgcn_mfma_f32_16x16x32_bf16(af[i], bfr[j], acc[i][j], 0, 0, 0);
    }
    __syncthreads();
  }
}

#define EPI_COORDS                              \
  const int tid  = threadIdx.x;                 \
  const int wave = tid >> 6;                    \
  const int lane = tid & 63;                    \
  const int lm   = lane & 15;                   \
  const int q    = lane >> 4;                   \
  const int wi   = (wave >> 1) * 64;            \
  const int wj   = (wave & 1) * 64;

#define ZERO_ACC(acc)                                            \
  _Pragma("unroll") for (int i = 0; i < 4; ++i)                  \
  _Pragma("unroll") for (int j = 0; j < 4; ++j)                  \
    acc[i][j] = (f32x4){0.f, 0.f, 0.f, 0.f};

// ---- convert fp32 -> bf16 hi/lo split, elementwise (vector x4)
__global__ __launch_bounds__(256) void k_cvt_split(const float* __restrict__ src,
                                                   bf16_t* __restrict__ hi,
                                                   bf16_t* __restrict__ lo)
{
  long i = ((long)blockIdx.x * 256 + threadIdx.x) * 4;
  float4 v = *(const float4*)(src + i);
  bf16_t h0 = (bf16_t)v.x, h1 = (bf16_t)v.y, h2 = (bf16_t)v.z, h3 = (bf16_t)v.w;
  bf16x4 hv = {h0, h1, h2, h3};
  bf16x4 lv = {(bf16_t)(v.x - (float)h0), (bf16_t)(v.y - (float)h1),
               (bf16_t)(v.z - (float)h2), (bf16_t)(v.w - (float)h3)};
  *(bf16x4*)(hi + i) = hv;
  *(bf16x4*)(lo + i) = lv;
}

// ---- fp32 transpose (R x C) -> bf16 (C x R), batched z (no lo)
__global__ __launch_bounds__(256) void k_transpose_cvt(const float* __restrict__ src,
                                                       bf16_t* __restrict__ hi,
                                                       int R, int C)
{
  __shared__ float t[32][33];
  long bofs = (long)blockIdx.z * R * C;
  int x = blockIdx.x * 32 + threadIdx.x;
  int y = blockIdx.y * 32 + threadIdx.y;
#pragma unroll
  for (int j = 0; j < 32; j += 8)
    t[threadIdx.y + j][threadIdx.x] = src[bofs + (long)(y + j) * C + x];
  __syncthreads();
  int x2 = blockIdx.y * 32 + threadIdx.x;
  int y2 = blockIdx.x * 32 + threadIdx.y;
#pragma unroll
  for (int j = 0; j < 32; j += 8) {
    float v  = t[threadIdx.x][threadIdx.y + j];
    hi[bofs + (long)(y2 + j) * R + x2] = (bf16_t)v;
  }
}

// ---- transpose+split the 3 weight matrices (768x768 each); z = branch
__global__ __launch_bounds__(256) void k_transpose_w3(const float* __restrict__ s0,
                                                      const float* __restrict__ s1,
                                                      const float* __restrict__ s2,
                                                      bf16_t* __restrict__ hi,
                                                      bf16_t* __restrict__ lo)
{
  __shared__ float t[32][33];
  int br = blockIdx.z;
  const float* src = (br == 0) ? s0 : ((br == 1) ? s1 : s2);
  long bofs = (long)br * 768 * 768;
  int x = blockIdx.x * 32 + threadIdx.x;
  int y = blockIdx.y * 32 + threadIdx.y;
#pragma unroll
  for (int j = 0; j < 32; j += 8)
    t[threadIdx.y + j][threadIdx.x] = src[(long)(y + j) * 768 + x];
  __syncthreads();
  int x2 = blockIdx.y * 32 + threadIdx.x;
  int y2 = blockIdx.x * 32 + threadIdx.y;
#pragma unroll
  for (int j = 0; j < 32; j += 8) {
    float v   = t[threadIdx.x][threadIdx.y + j];
    long idx  = bofs + (long)(y2 + j) * 768 + x2;
    bf16_t h  = (bf16_t)v;
    hi[idx] = h;
    lo[idx] = (bf16_t)(v - (float)h);
  }
}

// ---- GEMM1: T = node @ W, 3-pass hi/lo -> fp32-accurate, stored as hi/lo bf16
//      grid (64, 6, NBR); blockIdx.z = branch (stride 768*768 on WT, 8192*768 on T)
__global__ __launch_bounds__(256, 2) void k_gemm_tw(const bf16_t* __restrict__ nh,
                                                    const bf16_t* __restrict__ nl,
                                                    const bf16_t* __restrict__ WTh,
                                                    const bf16_t* __restrict__ WTl,
                                                    bf16_t* __restrict__ Thi,
                                                    bf16_t* __restrict__ Tlo)
{
  __shared__ __align__(16) bf16_t lA[128 * 64];
  __shared__ __align__(16) bf16_t lB[128 * 64];
  f32x4 acc[4][4];
  ZERO_ACC(acc);
  const long br = blockIdx.z;
  long aofs = (long)blockIdx.x * 128 * 768;
  long bofs = br * 768 * 768 + (long)blockIdx.y * 128 * 768;
  gemm_tile(nh + aofs, 768, WTh + bofs, 768, 12, lA, lB, acc);
  gemm_tile(nl + aofs, 768, WTh + bofs, 768, 12, lA, lB, acc);
  gemm_tile(nh + aofs, 768, WTl + bofs, 768, 12, lA, lB, acc);
  EPI_COORDS;
  long out0 = br * 8192 * 768;
  long row0 = (long)blockIdx.x * 128;
  long col0 = (long)blockIdx.y * 128;
#pragma unroll
  for (int i = 0; i < 4; ++i)
#pragma unroll
    for (int j = 0; j < 4; ++j)
#pragma unroll
      for (int r = 0; r < 4; ++r) {
        long row = row0 + wi + i * 16 + q * 4 + r;
        long col = col0 + wj + j * 16 + lm;
        float v  = acc[i][j][r];
        bf16_t h = (bf16_t)v;
        Thi[out0 + row * 768 + col] = h;
        Tlo[out0 + row * 768 + col] = (bf16_t)(v - (float)h);
      }
}

// ---- GEMM2: S = T @ node^T (3-pass hi/lo), masked by adj, fp32 out
//      grid (8, 8, 8*NBR); z: b = z&7, br = z>>3
__global__ __launch_bounds__(256, 2) void k_gemm_scores(const bf16_t* __restrict__ Thi,
                                                        const bf16_t* __restrict__ Tlo,
                                                        const bf16_t* __restrict__ nh,
                                                        const bf16_t* __restrict__ nl,
                                                        const int* __restrict__ adj0,
                                                        const int* __restrict__ adj1,
                                                        const int* __restrict__ adj2,
                                                        float* __restrict__ S)
{
  __shared__ __align__(16) bf16_t lA[128 * 64];
  __shared__ __align__(16) bf16_t lB[128 * 64];
  f32x4 acc[4][4];
  ZERO_ACC(acc);
  const int b  = blockIdx.z & 7;
  const int br = blockIdx.z >> 3;
  const int* adj = (br == 0) ? adj0 : ((br == 1) ? adj1 : adj2);
  long arow = ((long)br * 8192 + (long)b * 1024 + (long)blockIdx.x * 128) * 768;
  long brow = ((long)b * 1024 + (long)blockIdx.y * 128) * 768;
  gemm_tile(Thi + arow, 768, nh + brow, 768, 12, lA, lB, acc);
  gemm_tile(Tlo + arow, 768, nh + brow, 768, 12, lA, lB, acc);
  gemm_tile(Thi + arow, 768, nl + brow, 768, 12, lA, lB, acc);
  EPI_COORDS;
  const int* adjb = adj + (long)b * 1024 * 1024;
  float* Sb = S + ((long)br * 8 + b) * 1024 * 1024;
  long row0 = (long)blockIdx.x * 128;
  long col0 = (long)blockIdx.y * 128;
#pragma unroll
  for (int i = 0; i < 4; ++i)
#pragma unroll
    for (int j = 0; j < 4; ++j)
#pragma unroll
      for (int r = 0; r < 4; ++r) {
        long row = row0 + wi + i * 16 + q * 4 + r;
        long col = col0 + wj + j * 16 + lm;
        float v  = acc[i][j][r];
        v = (adjb[row * 1024 + col] == 1) ? v : -1e7f;
        Sb[row * 1024 + col] = v;
      }
}

// ---- row softmax: fp32 S[rows][1024] -> bf16 att
__global__ __launch_bounds__(256) void k_softmax(const float* __restrict__ S,
                                                 bf16_t* __restrict__ att)
{
  long row = blockIdx.x;
  const float4* p = (const float4*)(S + row * 1024);
  float4 v = p[threadIdx.x];
  float m = fmaxf(fmaxf(v.x, v.y), fmaxf(v.z, v.w));
#pragma unroll
  for (int off = 32; off; off >>= 1) m = fmaxf(m, __shfl_xor(m, off));
  __shared__ float redm[4];
  __shared__ float reds[4];
  int wave = threadIdx.x >> 6, lane = threadIdx.x & 63;
  if (lane == 0) redm[wave] = m;
  __syncthreads();
  m = fmaxf(fmaxf(redm[0], redm[1]), fmaxf(redm[2], redm[3]));
  float e0 = __expf(v.x - m), e1 = __expf(v.y - m), e2 = __expf(v.z - m), e3 = __expf(v.w - m);
  float s = e0 + e1 + e2 + e3;
#pragma unroll
  for (int off = 32; off; off >>= 1) s += __shfl_xor(s, off);
  if (lane == 0) reds[wave] = s;
  __syncthreads();
  s = reds[0] + reds[1] + reds[2] + reds[3];
  float inv = 1.0f / s;
  bf16x4 o = {(bf16_t)(e0 * inv), (bf16_t)(e1 * inv), (bf16_t)(e2 * inv), (bf16_t)(e3 * inv)};
  *(bf16x4*)(att + row * 1024 + threadIdx.x * 4) = o;
}

// ---- GEMM4: O = att @ node  -> wcat[:, (br_base+br)*768 : +768]
//      grid (8, 6, 8*NBR); z: b = z&7, br = z>>3
__global__ __launch_bounds__(256, 2) void k_gemm_pv(const bf16_t* __restrict__ att,
                                                    const bf16_t* __restrict__ nodeT,
                                                    bf16_t* __restrict__ wcat, int br_base)
{
  __shared__ __align__(16) bf16_t lA[128 * 64];
  __shared__ __align__(16) bf16_t lB[128 * 64];
  f32x4 acc[4][4];
  ZERO_ACC(acc);
  const int b  = blockIdx.z & 7;
  const int br = blockIdx.z >> 3;
  const bf16_t* A = att + (((long)br * 8 + b) * 1024 + (long)blockIdx.x * 128) * 1024;
  const bf16_t* B = nodeT + ((long)b * 768 + (long)blockIdx.y * 128) * 1024;
  gemm_tile(A, 1024, B, 1024, 16, lA, lB, acc);
  EPI_COORDS;
  bf16_t* C = wcat + (long)b * 1024 * 2304 + (long)(br_base + br) * 768;
  long row0 = (long)blockIdx.x * 128;
  long col0 = (long)blockIdx.y * 128;
#pragma unroll
  for (int i = 0; i < 4; ++i)
#pragma unroll
    for (int j = 0; j < 4; ++j)
#pragma unroll
      for (int r = 0; r < 4; ++r) {
        long row = row0 + wi + i * 16 + q * 4 + r;
        long col = col0 + wj + j * 16 + lm;
        C[row * 2304 + col] = (bf16_t)acc[i][j][r];
      }
}

// ---- GEMM5: out = wcat @ params (fp32 output)
__global__ __launch_bounds__(256, 2) void k_gemm_final(const bf16_t* __restrict__ wcat,
                                                       const bf16_t* __restrict__ paramsT,
                                                       float* __restrict__ out)
{
  __shared__ __align__(16) bf16_t lA[128 * 64];
  __shared__ __align__(16) bf16_t lB[128 * 64];
  f32x4 acc[4][4];
  ZERO_ACC(acc);
  const bf16_t* A = wcat + (long)blockIdx.x * 128 * 2304;
  const bf16_t* B = paramsT + (long)blockIdx.y * 128 * 2304;
  gemm_tile(A, 2304, B, 2304, 36, lA, lB, acc);
  EPI_COORDS;
  long row0 = (long)blockIdx.x * 128;
  long col0 = (long)blockIdx.y * 128;
#pragma unroll
  for (int i = 0; i < 4; ++i)
#pragma unroll
    for (int j = 0; j < 4; ++j)
#pragma unroll
      for (int r = 0; r < 4; ++r) {
        long row = row0 + wi + i * 16 + q * 4 + r;
        long col = col0 + wj + j * 16 + lm;
        out[row * 768 + col] = acc[i][j][r];
      }
}

extern "C" void kernel_launch(void* const* d_in, const int* in_sizes, int n_in,
                              void* d_out, int out_size, void* d_ws, size_t ws_size,
                              hipStream_t stream)
{
  const float* node    = (const float*)d_in[0];
  const int*   adjp[3] = {(const int*)d_in[1], (const int*)d_in[2], (const int*)d_in[3]};
  const float* Wp[3]   = {(const float*)d_in[4], (const float*)d_in[5], (const float*)d_in[6]};
  const float* params  = (const float*)d_in[7];
  float* out = (float*)d_out;

  const size_t SZ_WT3 = 3ull * 768 * 768 * 2;    // bf16 [3][768][768]
  const size_t SZ_PT  = 768ull * 2304 * 2;       // bf16 [768][2304]
  const size_t SZ_N   = 8ull * 1024 * 768 * 2;   // bf16 [8192][768]
  const size_t SZ_NT  = 8ull * 768 * 1024 * 2;   // bf16 [8][768][1024]
  const size_t SZ_T   = 8ull * 1024 * 768 * 2;   // bf16 [8192][768] (per branch)
  const size_t SZ_S   = 8ull * 1024 * 1024 * 4;  // fp32 [8][1024][1024] (per branch)
  const size_t SZ_ATT = 8ull * 1024 * 1024 * 2;  // bf16 (per branch)
  const size_t SZ_WC  = 8ull * 1024 * 2304 * 2;  // bf16 [8192][2304]

  const size_t FIXED   = 2 * SZ_WT3 + SZ_PT + 2 * SZ_N + SZ_NT + SZ_WC;
  const size_t TOTAL_M = FIXED + 3 * (2 * SZ_T + SZ_S + SZ_ATT);  // ~313 MB merged
  const size_t TOTAL_S = FIXED + 2 * SZ_T + SZ_S + SZ_ATT;        // ~162 MB serial
  if (ws_size < TOTAL_S) return;
  const bool merged = (ws_size >= TOTAL_M);
  const int NBR = merged ? 3 : 1;

  char* base = (char*)d_ws;
  size_t off = 0;
  bf16_t* WTh = (bf16_t*)(base + off); off += SZ_WT3;
  bf16_t* WTl = (bf16_t*)(base + off); off += SZ_WT3;
  bf16_t* paramsT = (bf16_t*)(base + off); off += SZ_PT;
  bf16_t* node_hi = (bf16_t*)(base + off); off += SZ_N;
  bf16_t* node_lo = (bf16_t*)(base + off); off += SZ_N;
  bf16_t* nodeT   = (bf16_t*)(base + off); off += SZ_NT;
  bf16_t* wcat    = (bf16_t*)(base + off); off += SZ_WC;
  bf16_t* Thi     = (bf16_t*)(base + off); off += (size_t)NBR * SZ_T;
  bf16_t* Tlo     = (bf16_t*)(base + off); off += (size_t)NBR * SZ_T;
  float*  S       = (float*)(base + off);  off += (size_t)NBR * SZ_S;
  bf16_t* att     = (bf16_t*)(base + off); off += (size_t)NBR * SZ_ATT;

  dim3 tb(32, 8);
  k_cvt_split<<<6144, 256, 0, stream>>>(node, node_hi, node_lo);
  k_transpose_cvt<<<dim3(24, 32, 8), tb, 0, stream>>>(node, nodeT, 1024, 768);
  k_transpose_w3<<<dim3(24, 24, 3), tb, 0, stream>>>(Wp[0], Wp[1], Wp[2], WTh, WTl);
  k_transpose_cvt<<<dim3(24, 72, 1), tb, 0, stream>>>(params, paramsT, 2304, 768);

  if (merged) {
    k_gemm_tw<<<dim3(64, 6, 3), 256, 0, stream>>>(node_hi, node_lo, WTh, WTl, Thi, Tlo);
    k_gemm_scores<<<dim3(8, 8, 24), 256, 0, stream>>>(Thi, Tlo, node_hi, node_lo,
                                                      adjp[0], adjp[1], adjp[2], S);
    k_softmax<<<24576, 256, 0, stream>>>(S, att);
    k_gemm_pv<<<dim3(8, 6, 24), 256, 0, stream>>>(att, nodeT, wcat, 0);
  } else {
    for (int br = 0; br < 3; ++br) {
      const bf16_t* wth = WTh + (size_t)br * 768 * 768;
      const bf16_t* wtl = WTl + (size_t)br * 768 * 768;
      k_gemm_tw<<<dim3(64, 6, 1), 256, 0, stream>>>(node_hi, node_lo, wth, wtl, Thi, Tlo);
      k_gemm_scores<<<dim3(8, 8, 8), 256, 0, stream>>>(Thi, Tlo, node_hi, node_lo,
                                                       adjp[br], adjp[br], adjp[br], S);
      k_softmax<<<8192, 256, 0, stream>>>(S, att);
      k_gemm_pv<<<dim3(8, 6, 8), 256, 0, stream>>>(att, nodeT, wcat, br);
    }
  }
  k_gemm_final<<<dim3(64, 6), 256, 0, stream>>>(wcat, paramsT, out);
}

// Round 5
// 848.865 us; speedup vs baseline: 1.0148x; 1.0077x over previous
//
#include <hip/hip_runtime.h>
#include <stdint.h>

typedef _Float16 f16_t;
typedef _Float16 f16x8 __attribute__((ext_vector_type(8)));
typedef _Float16 f16x4 __attribute__((ext_vector_type(4)));
typedef float f32x4 __attribute__((ext_vector_type(4)));

#define GLL16(g, l)                                                                   \
  __builtin_amdgcn_global_load_lds((const __attribute__((address_space(1))) uint32_t*)(g), \
                                   (__attribute__((address_space(3))) uint32_t*)(l),  \
                                   16, 0, 0)

// ---------------------------------------------------------------------------
// 128x128 GEMM tile mainloop (fp16). C(128x128) += A(128xK) * B(128xK)^T
// A,B row-major f16, leading dims lda/ldb. LDS chunk c = kq*128+row, 16B each.
// ---------------------------------------------------------------------------
__device__ __forceinline__ void gemm_tile(const f16_t* __restrict__ A, long lda,
                                          const f16_t* __restrict__ B, long ldb,
                                          int kTiles, f16_t* lA, f16_t* lB,
                                          f32x4 acc[4][4])
{
  const int tid  = threadIdx.x;
  const int wave = tid >> 6;
  const int lane = tid & 63;

  const f16_t* pA[4];
  const f16_t* pB[4];
  f16_t* lAb[4];
  f16_t* lBb[4];
#pragma unroll
  for (int i = 0; i < 4; ++i) {
    int c  = i * 256 + wave * 64 + lane;   // chunk id 0..1023
    int m  = c & 127;                      // row within tile
    int kq = c >> 7;                       // k-octet within BK=64
    pA[i]  = A + (long)m * lda + kq * 8;
    pB[i]  = B + (long)m * ldb + kq * 8;
    int cb = i * 256 + wave * 64;          // wave-uniform chunk base
    lAb[i] = lA + (long)cb * 8;
    lBb[i] = lB + (long)cb * 8;
  }
  const int lm = lane & 15;
  const int q  = lane >> 4;
  const int wi = (wave >> 1) * 64;
  const int wj = (wave & 1) * 64;

  for (int kt = 0; kt < kTiles; ++kt) {
    long ko = (long)kt * 64;
#pragma unroll
    for (int i = 0; i < 4; ++i) GLL16(pA[i] + ko, lAb[i]);
#pragma unroll
    for (int i = 0; i < 4; ++i) GLL16(pB[i] + ko, lBb[i]);
    __syncthreads();
#pragma unroll
    for (int s = 0; s < 2; ++s) {
      f16x8 af[4], bfr[4];
#pragma unroll
      for (int i = 0; i < 4; ++i)
        af[i] = *(const f16x8*)(lA + (((s * 4 + q) * 128) + wi + i * 16 + lm) * 8);
#pragma unroll
      for (int j = 0; j < 4; ++j)
        bfr[j] = *(const f16x8*)(lB + (((s * 4 + q) * 128) + wj + j * 16 + lm) * 8);
#pragma unroll
      for (int i = 0; i < 4; ++i)
#pragma unroll
        for (int j = 0; j < 4; ++j)
          acc[i][j] = __builtin_amdgcn_mfma_f32_16x16x32_f16(af[i], bfr[j], acc[i][j], 0, 0, 0);
    }
    __syncthreads();
  }
}

#define EPI_COORDS                              \
  const int tid  = threadIdx.x;                 \
  const int wave = tid >> 6;                    \
  const int lane = tid & 63;                    \
  const int lm   = lane & 15;                   \
  const int q    = lane >> 4;                   \
  const int wi   = (wave >> 1) * 64;            \
  const int wj   = (wave & 1) * 64;

#define ZERO_ACC(acc)                                            \
  _Pragma("unroll") for (int i = 0; i < 4; ++i)                  \
  _Pragma("unroll") for (int j = 0; j < 4; ++j)                  \
    acc[i][j] = (f32x4){0.f, 0.f, 0.f, 0.f};

// ---- convert fp32 -> f16 hi/lo split, elementwise (vector x4)
__global__ __launch_bounds__(256) void k_cvt_split(const float* __restrict__ src,
                                                   f16_t* __restrict__ hi,
                                                   f16_t* __restrict__ lo)
{
  long i = ((long)blockIdx.x * 256 + threadIdx.x) * 4;
  float4 v = *(const float4*)(src + i);
  f16_t h0 = (f16_t)v.x, h1 = (f16_t)v.y, h2 = (f16_t)v.z, h3 = (f16_t)v.w;
  f16x4 hv = {h0, h1, h2, h3};
  f16x4 lv = {(f16_t)(v.x - (float)h0), (f16_t)(v.y - (float)h1),
              (f16_t)(v.z - (float)h2), (f16_t)(v.w - (float)h3)};
  *(f16x4*)(hi + i) = hv;
  *(f16x4*)(lo + i) = lv;
}

// ---- fp32 transpose (R x C) -> f16 (C x R) hi (+ optional lo), batched z
__global__ __launch_bounds__(256) void k_transpose_cvt(const float* __restrict__ src,
                                                       f16_t* __restrict__ hi,
                                                       f16_t* __restrict__ lo,
                                                       int R, int C)
{
  __shared__ float t[32][33];
  long bofs = (long)blockIdx.z * R * C;
  int x = blockIdx.x * 32 + threadIdx.x;
  int y = blockIdx.y * 32 + threadIdx.y;
#pragma unroll
  for (int j = 0; j < 32; j += 8)
    t[threadIdx.y + j][threadIdx.x] = src[bofs + (long)(y + j) * C + x];
  __syncthreads();
  int x2 = blockIdx.y * 32 + threadIdx.x;
  int y2 = blockIdx.x * 32 + threadIdx.y;
#pragma unroll
  for (int j = 0; j < 32; j += 8) {
    float v  = t[threadIdx.x][threadIdx.y + j];
    long idx = bofs + (long)(y2 + j) * R + x2;
    f16_t h  = (f16_t)v;
    hi[idx] = h;
    if (lo) lo[idx] = (f16_t)(v - (float)h);
  }
}

// ---- GEMM1: T = node @ W, 3-pass (nh@Wh + nl@Wh + nh@Wl), T stored hi/lo f16
//      grid (64, 6, g); z = slot; branch = br_base + slot
__global__ __launch_bounds__(256, 2) void k_gemm_tw(const f16_t* __restrict__ nh,
                                                    const f16_t* __restrict__ nl,
                                                    const f16_t* __restrict__ Wh,
                                                    const f16_t* __restrict__ Wl,
                                                    f16_t* __restrict__ Thi,
                                                    f16_t* __restrict__ Tlo, int br_base)
{
  __shared__ __align__(16) f16_t lA[128 * 64];
  __shared__ __align__(16) f16_t lB[128 * 64];
  f32x4 acc[4][4];
  ZERO_ACC(acc);
  const int slot = blockIdx.z;
  const long br  = br_base + slot;
  long aofs = (long)blockIdx.x * 128 * 768;
  long bofs = br * 768 * 768 + (long)blockIdx.y * 128 * 768;
  gemm_tile(nh + aofs, 768, Wh + bofs, 768, 12, lA, lB, acc);
  gemm_tile(nl + aofs, 768, Wh + bofs, 768, 12, lA, lB, acc);
  gemm_tile(nh + aofs, 768, Wl + bofs, 768, 12, lA, lB, acc);
  EPI_COORDS;
  long out0 = (long)slot * 8192 * 768;
  long row0 = (long)blockIdx.x * 128;
  long col0 = (long)blockIdx.y * 128;
#pragma unroll
  for (int i = 0; i < 4; ++i)
#pragma unroll
    for (int j = 0; j < 4; ++j)
#pragma unroll
      for (int r = 0; r < 4; ++r) {
        long row = row0 + wi + i * 16 + q * 4 + r;
        long col = col0 + wj + j * 16 + lm;
        float v  = acc[i][j][r];
        f16_t h  = (f16_t)v;
        Thi[out0 + row * 768 + col] = h;
        Tlo[out0 + row * 768 + col] = (f16_t)(v - (float)h);
      }
}

// ---- GEMM2: S = T @ node^T, 3-pass (Thi@nh + Tlo@nh + Thi@nl), masked, fp32
//      grid (8, 8, 8g); z: b = z&7, slot = z>>3, branch = br_base+slot
__global__ __launch_bounds__(256, 2) void k_gemm_scores(const f16_t* __restrict__ Thi,
                                                        const f16_t* __restrict__ Tlo,
                                                        const f16_t* __restrict__ nh,
                                                        const f16_t* __restrict__ nl,
                                                        const int* __restrict__ adj0,
                                                        const int* __restrict__ adj1,
                                                        const int* __restrict__ adj2,
                                                        float* __restrict__ S, int br_base)
{
  __shared__ __align__(16) f16_t lA[128 * 64];
  __shared__ __align__(16) f16_t lB[128 * 64];
  f32x4 acc[4][4];
  ZERO_ACC(acc);
  const int b    = blockIdx.z & 7;
  const int slot = blockIdx.z >> 3;
  const int br   = br_base + slot;
  const int* adj = (br == 0) ? adj0 : ((br == 1) ? adj1 : adj2);
  long arow = (long)slot * 8192 * 768 + ((long)b * 1024 + (long)blockIdx.x * 128) * 768;
  long brow = ((long)b * 1024 + (long)blockIdx.y * 128) * 768;
  gemm_tile(Thi + arow, 768, nh + brow, 768, 12, lA, lB, acc);
  gemm_tile(Tlo + arow, 768, nh + brow, 768, 12, lA, lB, acc);
  gemm_tile(Thi + arow, 768, nl + brow, 768, 12, lA, lB, acc);
  EPI_COORDS;
  const int* adjb = adj + (long)b * 1024 * 1024;
  float* Sb = S + ((long)slot * 8 + b) * 1024 * 1024;
  long row0 = (long)blockIdx.x * 128;
  long col0 = (long)blockIdx.y * 128;
#pragma unroll
  for (int i = 0; i < 4; ++i)
#pragma unroll
    for (int j = 0; j < 4; ++j)
#pragma unroll
      for (int r = 0; r < 4; ++r) {
        long row = row0 + wi + i * 16 + q * 4 + r;
        long col = col0 + wj + j * 16 + lm;
        float v  = acc[i][j][r];
        v = (adjb[row * 1024 + col] == 1) ? v : -1e7f;
        Sb[row * 1024 + col] = v;
      }
}

// ---- row softmax: fp32 S row -> f16 att written IN-PLACE into the first half
//      of the same row (row-private overlay; att row stride = 2048 f16 elems)
__global__ __launch_bounds__(256) void k_softmax(float* __restrict__ S)
{
  long row = blockIdx.x;
  float* rowp = S + row * 1024;
  float4 v = ((const float4*)rowp)[threadIdx.x];
  float m = fmaxf(fmaxf(v.x, v.y), fmaxf(v.z, v.w));
#pragma unroll
  for (int off = 32; off; off >>= 1) m = fmaxf(m, __shfl_xor(m, off));
  __shared__ float redm[4];
  __shared__ float reds[4];
  int wave = threadIdx.x >> 6, lane = threadIdx.x & 63;
  if (lane == 0) redm[wave] = m;
  __syncthreads();   // also guarantees all row reads complete before any write
  m = fmaxf(fmaxf(redm[0], redm[1]), fmaxf(redm[2], redm[3]));
  float e0 = __expf(v.x - m), e1 = __expf(v.y - m), e2 = __expf(v.z - m), e3 = __expf(v.w - m);
  float s = e0 + e1 + e2 + e3;
#pragma unroll
  for (int off = 32; off; off >>= 1) s += __shfl_xor(s, off);
  if (lane == 0) reds[wave] = s;
  __syncthreads();
  s = reds[0] + reds[1] + reds[2] + reds[3];
  float inv = 1.0f / s;
  f16x4 o = {(f16_t)(e0 * inv), (f16_t)(e1 * inv), (f16_t)(e2 * inv), (f16_t)(e3 * inv)};
  *(f16x4*)((f16_t*)rowp + threadIdx.x * 4) = o;
}

// ---- GEMM4: w = att @ node -> written into the (dead) Thi slot buffer
//      grid (8, 6, 8g); att lives in S with row stride 2048
__global__ __launch_bounds__(256, 2) void k_gemm_pv(const float* __restrict__ S,
                                                    const f16_t* __restrict__ nodeT,
                                                    f16_t* __restrict__ Thi)
{
  __shared__ __align__(16) f16_t lA[128 * 64];
  __shared__ __align__(16) f16_t lB[128 * 64];
  f32x4 acc[4][4];
  ZERO_ACC(acc);
  const int b    = blockIdx.z & 7;
  const int slot = blockIdx.z >> 3;
  const f16_t* att = (const f16_t*)(S + (long)slot * 8 * 1024 * 1024);
  const f16_t* A = att + ((long)b * 1024 + (long)blockIdx.x * 128) * 2048;
  const f16_t* B = nodeT + ((long)b * 768 + (long)blockIdx.y * 128) * 1024;
  gemm_tile(A, 2048, B, 1024, 16, lA, lB, acc);
  EPI_COORDS;
  f16_t* C = Thi + (long)slot * 8192 * 768 + (long)b * 1024 * 768;
  long row0 = (long)blockIdx.x * 128;
  long col0 = (long)blockIdx.y * 128;
#pragma unroll
  for (int i = 0; i < 4; ++i)
#pragma unroll
    for (int j = 0; j < 4; ++j)
#pragma unroll
      for (int r = 0; r < 4; ++r) {
        long row = row0 + wi + i * 16 + q * 4 + r;
        long col = col0 + wj + j * 16 + lm;
        C[row * 768 + col] = (f16_t)acc[i][j][r];
      }
}

// ---- GEMM5 (accumulating): out (+)= sum_slot w_slot @ params[br_base+slot]
__global__ __launch_bounds__(256, 2) void k_gemm_final(const f16_t* __restrict__ Thi,
                                                       const f16_t* __restrict__ paramsT,
                                                       float* __restrict__ out,
                                                       int g, int br_base)
{
  __shared__ __align__(16) f16_t lA[128 * 64];
  __shared__ __align__(16) f16_t lB[128 * 64];
  f32x4 acc[4][4];
  ZERO_ACC(acc);
  for (int s = 0; s < g; ++s) {
    const f16_t* A = Thi + (long)s * 8192 * 768 + (long)blockIdx.x * 128 * 768;
    const f16_t* B = paramsT + (long)blockIdx.y * 128 * 2304 + (long)(br_base + s) * 768;
    gemm_tile(A, 768, B, 2304, 12, lA, lB, acc);
  }
  EPI_COORDS;
  long row0 = (long)blockIdx.x * 128;
  long col0 = (long)blockIdx.y * 128;
#pragma unroll
  for (int i = 0; i < 4; ++i)
#pragma unroll
    for (int j = 0; j < 4; ++j)
#pragma unroll
      for (int r = 0; r < 4; ++r) {
        long row = row0 + wi + i * 16 + q * 4 + r;
        long col = col0 + wj + j * 16 + lm;
        float v  = acc[i][j][r];
        if (br_base != 0) v += out[row * 768 + col];
        out[row * 768 + col] = v;
      }
}

extern "C" void kernel_launch(void* const* d_in, const int* in_sizes, int n_in,
                              void* d_out, int out_size, void* d_ws, size_t ws_size,
                              hipStream_t stream)
{
  const float* node    = (const float*)d_in[0];
  const int*   adjp[3] = {(const int*)d_in[1], (const int*)d_in[2], (const int*)d_in[3]};
  const float* Wp[3]   = {(const float*)d_in[4], (const float*)d_in[5], (const float*)d_in[6]};
  const float* params  = (const float*)d_in[7];
  float* out = (float*)d_out;

  const size_t SZ_W3 = 3ull * 768 * 768 * 2;     // f16 [3][768][768]
  const size_t SZ_PT = 768ull * 2304 * 2;        // f16 [768][2304]
  const size_t SZ_N  = 8192ull * 768 * 2;        // f16 [8192][768]
  const size_t SZ_NT = 8ull * 768 * 1024 * 2;    // f16 [8][768][1024]
  const size_t SZ_T  = 8192ull * 768 * 2;        // f16 per slot (Thi / Tlo)
  const size_t SZ_S  = 8ull * 1024 * 1024 * 4;   // fp32 per slot (S, later att overlay)
  const size_t FIXED = 2 * SZ_W3 + SZ_PT + 2 * SZ_N + SZ_NT;
  const size_t SLOT  = 2 * SZ_T + SZ_S;

  int NBR = 1;
  if (ws_size >= FIXED + 3 * SLOT) NBR = 3;
  else if (ws_size >= FIXED + 2 * SLOT) NBR = 2;
  else if (ws_size < FIXED + SLOT) return;  // can't run

  char* base = (char*)d_ws;
  size_t off = 0;
  f16_t* Wh      = (f16_t*)(base + off); off += SZ_W3;
  f16_t* Wl      = (f16_t*)(base + off); off += SZ_W3;
  f16_t* paramsT = (f16_t*)(base + off); off += SZ_PT;
  f16_t* node_hi = (f16_t*)(base + off); off += SZ_N;
  f16_t* node_lo = (f16_t*)(base + off); off += SZ_N;
  f16_t* nodeT   = (f16_t*)(base + off); off += SZ_NT;
  f16_t* Thi     = (f16_t*)(base + off); off += (size_t)NBR * SZ_T;
  f16_t* Tlo     = (f16_t*)(base + off); off += (size_t)NBR * SZ_T;
  float* S       = (float*)(base + off); off += (size_t)NBR * SZ_S;

  dim3 tb(32, 8);
  k_cvt_split<<<6144, 256, 0, stream>>>(node, node_hi, node_lo);
  k_transpose_cvt<<<dim3(24, 32, 8), tb, 0, stream>>>(node, nodeT, nullptr, 1024, 768);
  for (int br = 0; br < 3; ++br)
    k_transpose_cvt<<<dim3(24, 24, 1), tb, 0, stream>>>(Wp[br], Wh + (size_t)br * 768 * 768,
                                                        Wl + (size_t)br * 768 * 768, 768, 768);
  k_transpose_cvt<<<dim3(24, 72, 1), tb, 0, stream>>>(params, paramsT, nullptr, 2304, 768);

  int done = 0;
  while (done < 3) {
    int g = (3 - done < NBR) ? (3 - done) : NBR;
    k_gemm_tw<<<dim3(64, 6, g), 256, 0, stream>>>(node_hi, node_lo, Wh, Wl, Thi, Tlo, done);
    k_gemm_scores<<<dim3(8, 8, 8 * g), 256, 0, stream>>>(Thi, Tlo, node_hi, node_lo,
                                                         adjp[0], adjp[1], adjp[2], S, done);
    k_softmax<<<8192 * g, 256, 0, stream>>>(S);
    k_gemm_pv<<<dim3(8, 6, 8 * g), 256, 0, stream>>>(S, nodeT, Thi);
    k_gemm_final<<<dim3(64, 6), 256, 0, stream>>>(Thi, paramsT, out, g, done);
    done += g;
  }
}

// Round 6
// 700.005 us; speedup vs baseline: 1.2306x; 1.2127x over previous
//
#include <hip/hip_runtime.h>
#include <stdint.h>

typedef _Float16 f16_t;
typedef _Float16 f16x8 __attribute__((ext_vector_type(8)));
typedef _Float16 f16x4 __attribute__((ext_vector_type(4)));
typedef float f32x4 __attribute__((ext_vector_type(4)));

#define GLL16(g, l)                                                                   \
  __builtin_amdgcn_global_load_lds((const __attribute__((address_space(1))) uint32_t*)(g), \
                                   (__attribute__((address_space(3))) uint32_t*)(l),  \
                                   16, 0, 0)

// ---------------------------------------------------------------------------
// Plain 128x128 GEMM tile mainloop (BK=64). C += A(128xK) * B(128xK)^T
// ---------------------------------------------------------------------------
__device__ __forceinline__ void gemm_tile(const f16_t* __restrict__ A, long lda,
                                          const f16_t* __restrict__ B, long ldb,
                                          int kTiles, f16_t* lA, f16_t* lB,
                                          f32x4 acc[4][4])
{
  const int tid  = threadIdx.x;
  const int wave = tid >> 6;
  const int lane = tid & 63;

  const f16_t* pA[4];
  const f16_t* pB[4];
  f16_t* lAb[4];
  f16_t* lBb[4];
#pragma unroll
  for (int i = 0; i < 4; ++i) {
    int c  = i * 256 + wave * 64 + lane;
    int m  = c & 127;
    int kq = c >> 7;
    pA[i]  = A + (long)m * lda + kq * 8;
    pB[i]  = B + (long)m * ldb + kq * 8;
    int cb = i * 256 + wave * 64;
    lAb[i] = lA + (long)cb * 8;
    lBb[i] = lB + (long)cb * 8;
  }
  const int lm = lane & 15;
  const int q  = lane >> 4;
  const int wi = (wave >> 1) * 64;
  const int wj = (wave & 1) * 64;

  for (int kt = 0; kt < kTiles; ++kt) {
    long ko = (long)kt * 64;
#pragma unroll
    for (int i = 0; i < 4; ++i) GLL16(pA[i] + ko, lAb[i]);
#pragma unroll
    for (int i = 0; i < 4; ++i) GLL16(pB[i] + ko, lBb[i]);
    __syncthreads();
#pragma unroll
    for (int s = 0; s < 2; ++s) {
      f16x8 af[4], bfr[4];
#pragma unroll
      for (int i = 0; i < 4; ++i)
        af[i] = *(const f16x8*)(lA + (((s * 4 + q) * 128) + wi + i * 16 + lm) * 8);
#pragma unroll
      for (int j = 0; j < 4; ++j)
        bfr[j] = *(const f16x8*)(lB + (((s * 4 + q) * 128) + wj + j * 16 + lm) * 8);
#pragma unroll
      for (int i = 0; i < 4; ++i)
#pragma unroll
        for (int j = 0; j < 4; ++j)
          acc[i][j] = __builtin_amdgcn_mfma_f32_16x16x32_f16(af[i], bfr[j], acc[i][j], 0, 0, 0);
    }
    __syncthreads();
  }
}

// ---------------------------------------------------------------------------
// Fused hi/lo 3-product mainloop (BK=32): C += Ah*Bh^T + Al*Bh^T + Ah*Bl^T
// 4 LDS buffers of 128x32 f16 (8 KB each, 32 KB total). Per k-tile: 8 GLL16,
// 2 barriers, 48 MFMA -> 1.5x fewer barriers and 1.5x fewer loads than three
// separate passes.
// ---------------------------------------------------------------------------
__device__ __forceinline__ void gemm_tile3(const f16_t* __restrict__ Ah,
                                           const f16_t* __restrict__ Al, long lda,
                                           const f16_t* __restrict__ Bh,
                                           const f16_t* __restrict__ Bl, long ldb,
                                           int kTiles,
                                           f16_t* lAh, f16_t* lAl,
                                           f16_t* lBh, f16_t* lBl,
                                           f32x4 acc[4][4])
{
  const int tid  = threadIdx.x;
  const int wave = tid >> 6;
  const int lane = tid & 63;

  const f16_t* pAh[2]; const f16_t* pAl[2];
  const f16_t* pBh[2]; const f16_t* pBl[2];
  f16_t* dAh[2]; f16_t* dAl[2]; f16_t* dBh[2]; f16_t* dBl[2];
#pragma unroll
  for (int i = 0; i < 2; ++i) {
    int c  = i * 256 + wave * 64 + lane;   // chunk 0..511
    int m  = c & 127;
    int kq = c >> 7;                       // 0..3 (BK=32)
    long aoff = (long)m * lda + kq * 8;
    long boff = (long)m * ldb + kq * 8;
    pAh[i] = Ah + aoff;  pAl[i] = Al + aoff;
    pBh[i] = Bh + boff;  pBl[i] = Bl + boff;
    int cb = i * 256 + wave * 64;          // wave-uniform chunk base
    dAh[i] = lAh + (long)cb * 8;  dAl[i] = lAl + (long)cb * 8;
    dBh[i] = lBh + (long)cb * 8;  dBl[i] = lBl + (long)cb * 8;
  }
  const int lm = lane & 15;
  const int q  = lane >> 4;
  const int wi = (wave >> 1) * 64;
  const int wj = (wave & 1) * 64;

  for (int kt = 0; kt < kTiles; ++kt) {
    long ko = (long)kt * 32;
#pragma unroll
    for (int i = 0; i < 2; ++i) GLL16(pAh[i] + ko, dAh[i]);
#pragma unroll
    for (int i = 0; i < 2; ++i) GLL16(pAl[i] + ko, dAl[i]);
#pragma unroll
    for (int i = 0; i < 2; ++i) GLL16(pBh[i] + ko, dBh[i]);
#pragma unroll
    for (int i = 0; i < 2; ++i) GLL16(pBl[i] + ko, dBl[i]);
    __syncthreads();
    {
      f16x8 ah[4], al[4], bh[4], bl[4];
#pragma unroll
      for (int i = 0; i < 4; ++i) {
        int idx = (q * 128 + wi + i * 16 + lm) * 8;
        ah[i] = *(const f16x8*)(lAh + idx);
      }
#pragma unroll
      for (int j = 0; j < 4; ++j) {
        int idx = (q * 128 + wj + j * 16 + lm) * 8;
        bh[j] = *(const f16x8*)(lBh + idx);
      }
#pragma unroll
      for (int i = 0; i < 4; ++i)
#pragma unroll
        for (int j = 0; j < 4; ++j)
          acc[i][j] = __builtin_amdgcn_mfma_f32_16x16x32_f16(ah[i], bh[j], acc[i][j], 0, 0, 0);
#pragma unroll
      for (int i = 0; i < 4; ++i) {
        int idx = (q * 128 + wi + i * 16 + lm) * 8;
        al[i] = *(const f16x8*)(lAl + idx);
      }
#pragma unroll
      for (int i = 0; i < 4; ++i)
#pragma unroll
        for (int j = 0; j < 4; ++j)
          acc[i][j] = __builtin_amdgcn_mfma_f32_16x16x32_f16(al[i], bh[j], acc[i][j], 0, 0, 0);
#pragma unroll
      for (int j = 0; j < 4; ++j) {
        int idx = (q * 128 + wj + j * 16 + lm) * 8;
        bl[j] = *(const f16x8*)(lBl + idx);
      }
#pragma unroll
      for (int i = 0; i < 4; ++i)
#pragma unroll
        for (int j = 0; j < 4; ++j)
          acc[i][j] = __builtin_amdgcn_mfma_f32_16x16x32_f16(ah[i], bl[j], acc[i][j], 0, 0, 0);
    }
    __syncthreads();
  }
}

#define EPI_COORDS                              \
  const int tid  = threadIdx.x;                 \
  const int wave = tid >> 6;                    \
  const int lane = tid & 63;                    \
  const int lm   = lane & 15;                   \
  const int q    = lane >> 4;                   \
  const int wi   = (wave >> 1) * 64;            \
  const int wj   = (wave & 1) * 64;

#define ZERO_ACC(acc)                                            \
  _Pragma("unroll") for (int i = 0; i < 4; ++i)                  \
  _Pragma("unroll") for (int j = 0; j < 4; ++j)                  \
    acc[i][j] = (f32x4){0.f, 0.f, 0.f, 0.f};

// ---- convert fp32 -> f16 hi/lo split, elementwise (vector x4)
__global__ __launch_bounds__(256) void k_cvt_split(const float* __restrict__ src,
                                                   f16_t* __restrict__ hi,
                                                   f16_t* __restrict__ lo)
{
  long i = ((long)blockIdx.x * 256 + threadIdx.x) * 4;
  float4 v = *(const float4*)(src + i);
  f16_t h0 = (f16_t)v.x, h1 = (f16_t)v.y, h2 = (f16_t)v.z, h3 = (f16_t)v.w;
  f16x4 hv = {h0, h1, h2, h3};
  f16x4 lv = {(f16_t)(v.x - (float)h0), (f16_t)(v.y - (float)h1),
              (f16_t)(v.z - (float)h2), (f16_t)(v.w - (float)h3)};
  *(f16x4*)(hi + i) = hv;
  *(f16x4*)(lo + i) = lv;
}

// ---- fp32 transpose (R x C) -> f16 (C x R) hi (+ optional lo), batched z
__global__ __launch_bounds__(256) void k_transpose_cvt(const float* __restrict__ src,
                                                       f16_t* __restrict__ hi,
                                                       f16_t* __restrict__ lo,
                                                       int R, int C)
{
  __shared__ float t[32][33];
  long bofs = (long)blockIdx.z * R * C;
  int x = blockIdx.x * 32 + threadIdx.x;
  int y = blockIdx.y * 32 + threadIdx.y;
#pragma unroll
  for (int j = 0; j < 32; j += 8)
    t[threadIdx.y + j][threadIdx.x] = src[bofs + (long)(y + j) * C + x];
  __syncthreads();
  int x2 = blockIdx.y * 32 + threadIdx.x;
  int y2 = blockIdx.x * 32 + threadIdx.y;
#pragma unroll
  for (int j = 0; j < 32; j += 8) {
    float v  = t[threadIdx.x][threadIdx.y + j];
    long idx = bofs + (long)(y2 + j) * R + x2;
    f16_t h  = (f16_t)v;
    hi[idx] = h;
    if (lo) lo[idx] = (f16_t)(v - (float)h);
  }
}

// ---- GEMM1 (fused): T = node @ W  (nh@Wh + nl@Wh + nh@Wl), T stored hi/lo f16
__global__ __launch_bounds__(256, 2) void k_gemm_tw(const f16_t* __restrict__ nh,
                                                    const f16_t* __restrict__ nl,
                                                    const f16_t* __restrict__ Wh,
                                                    const f16_t* __restrict__ Wl,
                                                    f16_t* __restrict__ Thi,
                                                    f16_t* __restrict__ Tlo, int br_base)
{
  __shared__ __align__(16) f16_t lAh[128 * 32];
  __shared__ __align__(16) f16_t lAl[128 * 32];
  __shared__ __align__(16) f16_t lBh[128 * 32];
  __shared__ __align__(16) f16_t lBl[128 * 32];
  f32x4 acc[4][4];
  ZERO_ACC(acc);
  const int slot = blockIdx.z;
  const long br  = br_base + slot;
  long aofs = (long)blockIdx.x * 128 * 768;
  long bofs = br * 768 * 768 + (long)blockIdx.y * 128 * 768;
  gemm_tile3(nh + aofs, nl + aofs, 768, Wh + bofs, Wl + bofs, 768, 24,
             lAh, lAl, lBh, lBl, acc);
  EPI_COORDS;
  long out0 = (long)slot * 8192 * 768;
  long row0 = (long)blockIdx.x * 128;
  long col0 = (long)blockIdx.y * 128;
#pragma unroll
  for (int i = 0; i < 4; ++i)
#pragma unroll
    for (int j = 0; j < 4; ++j)
#pragma unroll
      for (int r = 0; r < 4; ++r) {
        long row = row0 + wi + i * 16 + q * 4 + r;
        long col = col0 + wj + j * 16 + lm;
        float v  = acc[i][j][r];
        f16_t h  = (f16_t)v;
        Thi[out0 + row * 768 + col] = h;
        Tlo[out0 + row * 768 + col] = (f16_t)(v - (float)h);
      }
}

// ---- GEMM2 (fused): S = T @ node^T (Thi@nh + Tlo@nh + Thi@nl), masked, fp32
//      grid (8, 8, 8g); XCD-supertile swizzled: id&7 = XCD owns g z-slices
__global__ __launch_bounds__(256, 2) void k_gemm_scores(const f16_t* __restrict__ Thi,
                                                        const f16_t* __restrict__ Tlo,
                                                        const f16_t* __restrict__ nh,
                                                        const f16_t* __restrict__ nl,
                                                        const int* __restrict__ adj0,
                                                        const int* __restrict__ adj1,
                                                        const int* __restrict__ adj2,
                                                        float* __restrict__ S, int br_base)
{
  __shared__ __align__(16) f16_t lAh[128 * 32];
  __shared__ __align__(16) f16_t lAl[128 * 32];
  __shared__ __align__(16) f16_t lBh[128 * 32];
  __shared__ __align__(16) f16_t lBl[128 * 32];
  f32x4 acc[4][4];
  ZERO_ACC(acc);
  // swizzle: assuming sequential block ids round-robin XCDs, give XCD k the
  // z-slices [k*g, (k+1)*g) traversed slice-by-slice for L2 locality.
  const int g    = gridDim.z >> 3;
  int id   = blockIdx.x + (blockIdx.y << 3) + (blockIdx.z << 6);
  int xcd  = id & 7;
  int step = id >> 3;
  int zz   = xcd * g + (step >> 6);
  int s    = step & 63;
  int bx   = s & 7;
  int by   = s >> 3;
  const int b    = zz & 7;
  const int slot = zz >> 3;
  const int br   = br_base + slot;
  const int* adj = (br == 0) ? adj0 : ((br == 1) ? adj1 : adj2);
  long arow = (long)slot * 8192 * 768 + ((long)b * 1024 + (long)bx * 128) * 768;
  long brow = ((long)b * 1024 + (long)by * 128) * 768;
  gemm_tile3(Thi + arow, Tlo + arow, 768, nh + brow, nl + brow, 768, 24,
             lAh, lAl, lBh, lBl, acc);
  EPI_COORDS;
  const int* adjb = adj + (long)b * 1024 * 1024;
  float* Sb = S + ((long)slot * 8 + b) * 1024 * 1024;
  long row0 = (long)bx * 128;
  long col0 = (long)by * 128;
#pragma unroll
  for (int i = 0; i < 4; ++i)
#pragma unroll
    for (int j = 0; j < 4; ++j)
#pragma unroll
      for (int r = 0; r < 4; ++r) {
        long row = row0 + wi + i * 16 + q * 4 + r;
        long col = col0 + wj + j * 16 + lm;
        float v  = acc[i][j][r];
        v = (adjb[row * 1024 + col] == 1) ? v : -1e7f;
        Sb[row * 1024 + col] = v;
      }
}

// ---- row softmax: fp32 S row -> f16 att written IN-PLACE (row stride 2048 f16)
__global__ __launch_bounds__(256) void k_softmax(float* __restrict__ S)
{
  long row = blockIdx.x;
  float* rowp = S + row * 1024;
  float4 v = ((const float4*)rowp)[threadIdx.x];
  float m = fmaxf(fmaxf(v.x, v.y), fmaxf(v.z, v.w));
#pragma unroll
  for (int off = 32; off; off >>= 1) m = fmaxf(m, __shfl_xor(m, off));
  __shared__ float redm[4];
  __shared__ float reds[4];
  int wave = threadIdx.x >> 6, lane = threadIdx.x & 63;
  if (lane == 0) redm[wave] = m;
  __syncthreads();   // also: all row reads complete before any in-place write
  m = fmaxf(fmaxf(redm[0], redm[1]), fmaxf(redm[2], redm[3]));
  float e0 = __expf(v.x - m), e1 = __expf(v.y - m), e2 = __expf(v.z - m), e3 = __expf(v.w - m);
  float s = e0 + e1 + e2 + e3;
#pragma unroll
  for (int off = 32; off; off >>= 1) s += __shfl_xor(s, off);
  if (lane == 0) reds[wave] = s;
  __syncthreads();
  s = reds[0] + reds[1] + reds[2] + reds[3];
  float inv = 1.0f / s;
  f16x4 o = {(f16_t)(e0 * inv), (f16_t)(e1 * inv), (f16_t)(e2 * inv), (f16_t)(e3 * inv)};
  *(f16x4*)((f16_t*)rowp + threadIdx.x * 4) = o;
}

// ---- GEMM4: w = att @ node -> written into the (dead) Thi slot buffer
__global__ __launch_bounds__(256, 2) void k_gemm_pv(const float* __restrict__ S,
                                                    const f16_t* __restrict__ nodeT,
                                                    f16_t* __restrict__ Thi)
{
  __shared__ __align__(16) f16_t lA[128 * 64];
  __shared__ __align__(16) f16_t lB[128 * 64];
  f32x4 acc[4][4];
  ZERO_ACC(acc);
  const int b    = blockIdx.z & 7;
  const int slot = blockIdx.z >> 3;
  const f16_t* att = (const f16_t*)(S + (long)slot * 8 * 1024 * 1024);
  const f16_t* A = att + ((long)b * 1024 + (long)blockIdx.x * 128) * 2048;
  const f16_t* B = nodeT + ((long)b * 768 + (long)blockIdx.y * 128) * 1024;
  gemm_tile(A, 2048, B, 1024, 16, lA, lB, acc);
  EPI_COORDS;
  f16_t* C = Thi + (long)slot * 8192 * 768 + (long)b * 1024 * 768;
  long row0 = (long)blockIdx.x * 128;
  long col0 = (long)blockIdx.y * 128;
#pragma unroll
  for (int i = 0; i < 4; ++i)
#pragma unroll
    for (int j = 0; j < 4; ++j)
#pragma unroll
      for (int r = 0; r < 4; ++r) {
        long row = row0 + wi + i * 16 + q * 4 + r;
        long col = col0 + wj + j * 16 + lm;
        C[row * 768 + col] = (f16_t)acc[i][j][r];
      }
}

// ---- GEMM5 (accumulating): out (+)= sum_slot w_slot @ params[br_base+slot]
__global__ __launch_bounds__(256, 2) void k_gemm_final(const f16_t* __restrict__ Thi,
                                                       const f16_t* __restrict__ paramsT,
                                                       float* __restrict__ out,
                                                       int g, int br_base)
{
  __shared__ __align__(16) f16_t lA[128 * 64];
  __shared__ __align__(16) f16_t lB[128 * 64];
  f32x4 acc[4][4];
  ZERO_ACC(acc);
  for (int s = 0; s < g; ++s) {
    const f16_t* A = Thi + (long)s * 8192 * 768 + (long)blockIdx.x * 128 * 768;
    const f16_t* B = paramsT + (long)blockIdx.y * 128 * 2304 + (long)(br_base + s) * 768;
    gemm_tile(A, 768, B, 2304, 12, lA, lB, acc);
  }
  EPI_COORDS;
  long row0 = (long)blockIdx.x * 128;
  long col0 = (long)blockIdx.y * 128;
#pragma unroll
  for (int i = 0; i < 4; ++i)
#pragma unroll
    for (int j = 0; j < 4; ++j)
#pragma unroll
      for (int r = 0; r < 4; ++r) {
        long row = row0 + wi + i * 16 + q * 4 + r;
        long col = col0 + wj + j * 16 + lm;
        float v  = acc[i][j][r];
        if (br_base != 0) v += out[row * 768 + col];
        out[row * 768 + col] = v;
      }
}

extern "C" void kernel_launch(void* const* d_in, const int* in_sizes, int n_in,
                              void* d_out, int out_size, void* d_ws, size_t ws_size,
                              hipStream_t stream)
{
  const float* node    = (const float*)d_in[0];
  const int*   adjp[3] = {(const int*)d_in[1], (const int*)d_in[2], (const int*)d_in[3]};
  const float* Wp[3]   = {(const float*)d_in[4], (const float*)d_in[5], (const float*)d_in[6]};
  const float* params  = (const float*)d_in[7];
  float* out = (float*)d_out;

  const size_t SZ_W3 = 3ull * 768 * 768 * 2;     // f16 [3][768][768]
  const size_t SZ_PT = 768ull * 2304 * 2;        // f16 [768][2304]
  const size_t SZ_N  = 8192ull * 768 * 2;        // f16 [8192][768]
  const size_t SZ_NT = 8ull * 768 * 1024 * 2;    // f16 [8][768][1024]
  const size_t SZ_T  = 8192ull * 768 * 2;        // f16 per slot (Thi / Tlo)
  const size_t SZ_S  = 8ull * 1024 * 1024 * 4;   // fp32 per slot (S, later att overlay)
  const size_t FIXED = 2 * SZ_W3 + SZ_PT + 2 * SZ_N + SZ_NT;
  const size_t SLOT  = 2 * SZ_T + SZ_S;

  int NBR = 1;
  if (ws_size >= FIXED + 3 * SLOT) NBR = 3;
  else if (ws_size >= FIXED + 2 * SLOT) NBR = 2;
  else if (ws_size < FIXED + SLOT) return;  // can't run

  char* base = (char*)d_ws;
  size_t off = 0;
  f16_t* Wh      = (f16_t*)(base + off); off += SZ_W3;
  f16_t* Wl      = (f16_t*)(base + off); off += SZ_W3;
  f16_t* paramsT = (f16_t*)(base + off); off += SZ_PT;
  f16_t* node_hi = (f16_t*)(base + off); off += SZ_N;
  f16_t* node_lo = (f16_t*)(base + off); off += SZ_N;
  f16_t* nodeT   = (f16_t*)(base + off); off += SZ_NT;
  f16_t* Thi     = (f16_t*)(base + off); off += (size_t)NBR * SZ_T;
  f16_t* Tlo     = (f16_t*)(base + off); off += (size_t)NBR * SZ_T;
  float* S       = (float*)(base + off); off += (size_t)NBR * SZ_S;

  dim3 tb(32, 8);
  k_cvt_split<<<6144, 256, 0, stream>>>(node, node_hi, node_lo);
  k_transpose_cvt<<<dim3(24, 32, 8), tb, 0, stream>>>(node, nodeT, nullptr, 1024, 768);
  for (int br = 0; br < 3; ++br)
    k_transpose_cvt<<<dim3(24, 24, 1), tb, 0, stream>>>(Wp[br], Wh + (size_t)br * 768 * 768,
                                                        Wl + (size_t)br * 768 * 768, 768, 768);
  k_transpose_cvt<<<dim3(24, 72, 1), tb, 0, stream>>>(params, paramsT, nullptr, 2304, 768);

  int done = 0;
  while (done < 3) {
    int g = (3 - done < NBR) ? (3 - done) : NBR;
    k_gemm_tw<<<dim3(64, 6, g), 256, 0, stream>>>(node_hi, node_lo, Wh, Wl, Thi, Tlo, done);
    k_gemm_scores<<<dim3(8, 8, 8 * g), 256, 0, stream>>>(Thi, Tlo, node_hi, node_lo,
                                                         adjp[0], adjp[1], adjp[2], S, done);
    k_softmax<<<8192 * g, 256, 0, stream>>>(S);
    k_gemm_pv<<<dim3(8, 6, 8 * g), 256, 0, stream>>>(S, nodeT, Thi);
    k_gemm_final<<<dim3(64, 6), 256, 0, stream>>>(Thi, paramsT, out, g, done);
    done += g;
  }
}